// Round 3
// baseline (98.180 us; speedup 1.0000x reference)
//
#include <hip/hip_runtime.h>
#include <hip/hip_bf16.h>

#define BB 8
#define SS 8192
#define FF 512
#define EE 128
#define CC 1000

typedef __bf16 bf16x8 __attribute__((ext_vector_type(8)));
typedef float  f32x4  __attribute__((ext_vector_type(4)));

// ---------------- K0: transpose-convert W (F,E) f32 -> Wt (E,F) bf16 ----------------
__global__ void k0_wt(const float* __restrict__ W, __bf16* __restrict__ Wt) {
    int idx = blockIdx.x * 256 + threadIdx.x;   // 65536 = F*E
    int e = idx & (EE - 1);
    int f = idx >> 7;
    Wt[e * FF + f] = (__bf16)W[f * EE + e];
}

// ---------------- FUSED: scores -> exp weights -> weighted partial sums ----------------
// grid = 1024 blocks (b = bid>>7, chunk = bid&127 of 64 rows), 256 threads (4 waves)
// 4 blocks/CU co-resident: LDS ~25KB, VGPR capped at 128 via launch_bounds(256,4).
__global__ __launch_bounds__(256, 4) void k_fused(
    const float* __restrict__ x,          // (B,F)
    const float* __restrict__ sx,         // (B,S,F)
    const __bf16* __restrict__ Wt,        // (E,F) bf16
    const float* __restrict__ y,          // (B,S,C)
    float* __restrict__ pout,             // (B,128,C) partial numerators
    float* __restrict__ pden)             // (B,128)   partial denominators
{
    __shared__ __bf16 lA[2][4][64][8];    // 8 KB  (diff tile, 64 rows x 32 k)
    __shared__ __bf16 lB[2][4][128][8];   // 16 KB (W tile, 128 e x 32 k)
    __shared__ float  scp[2][64];
    __shared__ float  wv[64];

    const int tid   = threadIdx.x;
    const int b     = blockIdx.x >> 7;
    const int chunk = blockIdx.x & 127;
    const int srow0 = chunk << 6;
    const float* Xb = sx + ((size_t)b * SS + srow0) * FF;
    const float* xb = x + b * FF;

    // A staging: row = tid>>2 (0..63), kq = tid&3 (8 k-floats each)
    const int rowA = tid >> 2;
    const int kq   = tid & 3;
    // B staging: e = tid>>1 (0..127), kh = tid&1 (16 k each = k-groups 2kh,2kh+1)
    const int rowB = tid >> 1;
    const int kh   = tid & 1;

    const int lane = tid & 63;
    const int w    = tid >> 6;        // wave 0..3
    const int wrow = (w >> 1) * 32;   // wave tile: 32 rows x 64 cols
    const int wcol = (w & 1) * 64;
    const int lg   = lane >> 4;       // k-group 0..3
    const int lr   = lane & 15;

    f32x4 acc[2][4];
    #pragma unroll
    for (int m = 0; m < 2; m++)
        #pragma unroll
        for (int n = 0; n < 4; n++) { f32x4 z = {0.f, 0.f, 0.f, 0.f}; acc[m][n] = z; }

    float4 sReg[2], xReg[2];

    auto LOADT = [&](int t) {
        const float* pS = Xb + (size_t)rowA * FF + t * 32 + kq * 8;
        const float* pX = xb + t * 32 + kq * 8;
        #pragma unroll
        for (int i = 0; i < 2; i++) {
            sReg[i] = *(const float4*)(pS + 4 * i);
            xReg[i] = *(const float4*)(pX + 4 * i);
        }
    };
    auto WRITET = [&](int buf) {
        __bf16 d[8];
        #pragma unroll
        for (int i = 0; i < 2; i++) {
            d[4 * i + 0] = (__bf16)(xReg[i].x - sReg[i].x);
            d[4 * i + 1] = (__bf16)(xReg[i].y - sReg[i].y);
            d[4 * i + 2] = (__bf16)(xReg[i].z - sReg[i].z);
            d[4 * i + 3] = (__bf16)(xReg[i].w - sReg[i].w);
        }
        *(bf16x8*)&lA[buf][kq][rowA][0] = *(bf16x8*)&d[0];
    };
    auto STAGEB = [&](int buf, int t) {
        const __bf16* pW = Wt + (size_t)rowB * FF + t * 32 + kh * 16;
        bf16x8 w0 = *(const bf16x8*)(pW);
        bf16x8 w1 = *(const bf16x8*)(pW + 8);
        *(bf16x8*)&lB[buf][kh * 2 + 0][rowB][0] = w0;
        *(bf16x8*)&lB[buf][kh * 2 + 1][rowB][0] = w1;
    };

    // ---- Phase 1: diff-GEMM over K=512, tile 64x128 ----
    LOADT(0);
    STAGEB(0, 0);
    WRITET(0);
    __syncthreads();

    for (int t = 0; t < 16; t++) {
        const int cur = t & 1;
        if (t < 15) {
            LOADT(t + 1);
            STAGEB(cur ^ 1, t + 1);
        }
        bf16x8 af[2], bfr[4];
        #pragma unroll
        for (int m = 0; m < 2; m++)
            af[m] = *(const bf16x8*)&lA[cur][lg][wrow + m * 16 + lr][0];
        #pragma unroll
        for (int n = 0; n < 4; n++)
            bfr[n] = *(const bf16x8*)&lB[cur][lg][wcol + n * 16 + lr][0];
        #pragma unroll
        for (int m = 0; m < 2; m++)
            #pragma unroll
            for (int n = 0; n < 4; n++)
                acc[m][n] = __builtin_amdgcn_mfma_f32_16x16x32_bf16(af[m], bfr[n], acc[m][n], 0, 0, 0);
        if (t < 15) WRITET(cur ^ 1);
        __syncthreads();
    }

    // ---- Epilogue: per-row ||.||^2 -> wv[row] = exp(-sqrt(.)) ----
    // C/D layout: col = wcol + n*16 + lr ; row = wrow + m*16 + lg*4 + j
    float rp[2][4];
    #pragma unroll
    for (int m = 0; m < 2; m++)
        #pragma unroll
        for (int j = 0; j < 4; j++) {
            float s = 0.f;
            #pragma unroll
            for (int n = 0; n < 4; n++) { float v = acc[m][n][j]; s += v * v; }
            rp[m][j] = s;
        }
    #pragma unroll
    for (int mask = 1; mask < 16; mask <<= 1)
        #pragma unroll
        for (int m = 0; m < 2; m++)
            #pragma unroll
            for (int j = 0; j < 4; j++)
                rp[m][j] += __shfl_xor(rp[m][j], mask);

    if (lr == 0) {
        #pragma unroll
        for (int m = 0; m < 2; m++)
            #pragma unroll
            for (int j = 0; j < 4; j++)
                scp[w & 1][wrow + m * 16 + lg * 4 + j] = rp[m][j];
    }
    __syncthreads();
    if (tid < 64)
        wv[tid] = expf(-sqrtf(scp[0][tid] + scp[1][tid]));
    __syncthreads();

    // partial denominator: wave 0 reduces wv[0..63]
    if (w == 0) {
        float d = wv[lane];
        #pragma unroll
        for (int mask = 1; mask < 64; mask <<= 1)
            d += __shfl_xor(d, mask);
        if (lane == 0) pden[b * 128 + chunk] = d;
    }

    // ---- Phase 2: weighted partial sum over support_y (64 rows x 1000 classes) ----
    if (tid < 250) {
        float a0 = 0.f, a1 = 0.f, a2 = 0.f, a3 = 0.f;
        const float* base = y + ((size_t)b * SS + srow0) * CC + tid * 4;
        #pragma unroll 8
        for (int r = 0; r < 64; r++) {
            float4 v = *(const float4*)(base + (size_t)r * CC);
            float wgt = wv[r];
            a0 += wgt * v.x; a1 += wgt * v.y; a2 += wgt * v.z; a3 += wgt * v.w;
        }
        float4 res = {a0, a1, a2, a3};
        *(float4*)(pout + ((size_t)(b * 128 + chunk)) * CC + tid * 4) = res;
    }
}

// ---------------- K4: final reduction over 128 chunks ----------------
__global__ void k4_final(const float* __restrict__ pout, const float* __restrict__ pden,
                         float* __restrict__ out) {
    int idx = blockIdx.x * 256 + threadIdx.x;
    if (idx >= BB * CC) return;
    int b = idx / CC, c = idx % CC;
    float den = 0.f;
    #pragma unroll 8
    for (int k = 0; k < 128; k++) den += pden[b * 128 + k];
    float num = 0.f;
    #pragma unroll 8
    for (int k = 0; k < 128; k++) num += pout[((size_t)(b * 128 + k)) * CC + c];
    out[idx] = num / den;
}

extern "C" void kernel_launch(void* const* d_in, const int* in_sizes, int n_in,
                              void* d_out, int out_size, void* d_ws, size_t ws_size,
                              hipStream_t stream) {
    const float* x  = (const float*)d_in[0];
    const float* sx = (const float*)d_in[1];
    const float* sy = (const float*)d_in[2];
    const float* W  = (const float*)d_in[3];

    char* ws = (char*)d_ws;
    __bf16* Wt   = (__bf16*)(ws);                        // 131072 B
    float*  pout = (float*)(ws + 131072);                // 4096000 B
    float*  pden = (float*)(ws + 131072 + 4096000);      // 4096 B

    k0_wt<<<256, 256, 0, stream>>>(W, Wt);
    k_fused<<<1024, 256, 0, stream>>>(x, sx, Wt, sy, pout, pden);
    k4_final<<<32, 256, 0, stream>>>(pout, pden, (float*)d_out);
}

// Round 4
// 91.819 us; speedup vs baseline: 1.0693x; 1.0693x over previous
//
#include <hip/hip_runtime.h>
#include <hip/hip_bf16.h>

#define BB 8
#define SS 8192
#define FF 512
#define EE 128
#define CC 1000

typedef __bf16 bf16x8 __attribute__((ext_vector_type(8)));
typedef float  f32x4  __attribute__((ext_vector_type(4)));

// ---------------- K0: transpose-convert W (F,E) f32 -> Wt (E,F) bf16 ----------------
__global__ void k0_wt(const float* __restrict__ W, __bf16* __restrict__ Wt) {
    int idx = blockIdx.x * 256 + threadIdx.x;   // 65536 = F*E
    int e = idx & (EE - 1);
    int f = idx >> 7;
    Wt[e * FF + f] = (__bf16)W[f * EE + e];
}

// ---------------- FUSED: scores -> exp weights -> weighted partial sums ----------------
// grid = 512 blocks (b = bid>>6, chunk = bid&63 of 128 rows), 256 threads (4 waves)
// Phase 1: reg-staged diff-GEMM, sx loads issued TWO K-steps ahead (full-step latency slack).
__global__ __launch_bounds__(256) void k_fused(
    const float* __restrict__ x,          // (B,F)
    const float* __restrict__ sx,         // (B,S,F)
    const __bf16* __restrict__ Wt,        // (E,F) bf16
    const float* __restrict__ y,          // (B,S,C)
    float* __restrict__ pout,             // (B,64,C) partial numerators
    float* __restrict__ pden)             // (B,64)   partial denominators
{
    __shared__ __bf16 lA[2][4][128][8];   // 16 KB diff tile (128 rows x 32 k)
    __shared__ __bf16 lB[2][4][128][8];   // 16 KB W tile (128 e x 32 k)
    __shared__ float  scp[2][128];
    __shared__ float  wv[128];

    const int tid   = threadIdx.x;
    const int b     = blockIdx.x >> 6;
    const int chunk = blockIdx.x & 63;
    const int srow0 = chunk << 7;
    const float* Xb = sx + ((size_t)b * SS + srow0) * FF;
    const float* xb = x + b * FF;

    const int row  = tid >> 1;        // 0..127 (also 'e' for B staging)
    const int kh   = tid & 1;         // which 16-float half of the 32-k step
    const int lane = tid & 63;
    const int w    = tid >> 6;        // wave 0..3
    const int wrow = (w >> 1) * 64;
    const int wcol = (w & 1) * 64;
    const int lg   = lane >> 4;       // k-group 0..3
    const int lr   = lane & 15;

    f32x4 acc[4][4];
    #pragma unroll
    for (int m = 0; m < 4; m++)
        #pragma unroll
        for (int n = 0; n < 4; n++) { f32x4 z = {0.f, 0.f, 0.f, 0.f}; acc[m][n] = z; }

    // two in-flight sx register sets (2-step-ahead pipeline)
    float4 sA[4], sB[4];      // named sets (compile-time selected via full unroll)
    float4 xReg[4];
    bf16x8 bReg0, bReg1;

    auto LOADS_A = [&](int t) {
        const float* p = Xb + (size_t)row * FF + t * 32 + kh * 16;
        #pragma unroll
        for (int i = 0; i < 4; i++) sA[i] = *(const float4*)(p + 4 * i);
    };
    auto LOADS_B = [&](int t) {
        const float* p = Xb + (size_t)row * FF + t * 32 + kh * 16;
        #pragma unroll
        for (int i = 0; i < 4; i++) sB[i] = *(const float4*)(p + 4 * i);
    };
    auto LOADX = [&](int t) {
        const float* p = xb + t * 32 + kh * 16;
        #pragma unroll
        for (int i = 0; i < 4; i++) xReg[i] = *(const float4*)(p + 4 * i);
    };
    auto LOADB = [&](int t) {
        const __bf16* pW = Wt + (size_t)row * FF + t * 32 + kh * 16;
        bReg0 = *(const bf16x8*)(pW);
        bReg1 = *(const bf16x8*)(pW + 8);
    };
    auto WRITE_FROM_A = [&](int buf) {
        __bf16 d[16];
        #pragma unroll
        for (int i = 0; i < 4; i++) {
            d[4*i+0] = (__bf16)(xReg[i].x - sA[i].x);
            d[4*i+1] = (__bf16)(xReg[i].y - sA[i].y);
            d[4*i+2] = (__bf16)(xReg[i].z - sA[i].z);
            d[4*i+3] = (__bf16)(xReg[i].w - sA[i].w);
        }
        *(bf16x8*)&lA[buf][kh*2+0][row][0] = *(bf16x8*)&d[0];
        *(bf16x8*)&lA[buf][kh*2+1][row][0] = *(bf16x8*)&d[8];
        *(bf16x8*)&lB[buf][kh*2+0][row][0] = bReg0;
        *(bf16x8*)&lB[buf][kh*2+1][row][0] = bReg1;
    };
    auto WRITE_FROM_B = [&](int buf) {
        __bf16 d[16];
        #pragma unroll
        for (int i = 0; i < 4; i++) {
            d[4*i+0] = (__bf16)(xReg[i].x - sB[i].x);
            d[4*i+1] = (__bf16)(xReg[i].y - sB[i].y);
            d[4*i+2] = (__bf16)(xReg[i].z - sB[i].z);
            d[4*i+3] = (__bf16)(xReg[i].w - sB[i].w);
        }
        *(bf16x8*)&lA[buf][kh*2+0][row][0] = *(bf16x8*)&d[0];
        *(bf16x8*)&lA[buf][kh*2+1][row][0] = *(bf16x8*)&d[8];
        *(bf16x8*)&lB[buf][kh*2+0][row][0] = bReg0;
        *(bf16x8*)&lB[buf][kh*2+1][row][0] = bReg1;
    };
    auto MFMA_STEP = [&](int buf) {
        bf16x8 af[4], bfr[4];
        #pragma unroll
        for (int m = 0; m < 4; m++)
            af[m] = *(const bf16x8*)&lA[buf][lg][wrow + m * 16 + lr][0];
        #pragma unroll
        for (int n = 0; n < 4; n++)
            bfr[n] = *(const bf16x8*)&lB[buf][lg][wcol + n * 16 + lr][0];
        #pragma unroll
        for (int m = 0; m < 4; m++)
            #pragma unroll
            for (int n = 0; n < 4; n++)
                acc[m][n] = __builtin_amdgcn_mfma_f32_16x16x32_bf16(af[m], bfr[n], acc[m][n], 0, 0, 0);
    };

    // ---- Prologue: sets A=t0, B=t1 in flight; write t0 -> buf0 ----
    LOADS_A(0);
    LOADS_B(1);
    LOADX(0);
    LOADB(0);
    WRITE_FROM_A(0);          // waits only on t0 regs; t1 stays in flight
    __syncthreads();

    // ---- K-loop, fully unrolled: at step t, issue t+2, compute t, write t+1 ----
    #pragma unroll
    for (int t = 0; t < 16; t++) {
        const int cur = t & 1;
        if (t + 2 < 16) {
            if ((t & 1) == 0) LOADS_A(t + 2);   // set parity: t even -> A holds t+2
            else              LOADS_B(t + 2);
        }
        if (t + 1 < 16) { LOADX(t + 1); LOADB(t + 1); }
        MFMA_STEP(cur);
        if (t + 1 < 16) {
            if ((t & 1) == 0) WRITE_FROM_B(cur ^ 1);   // t+1 lives in the other set
            else              WRITE_FROM_A(cur ^ 1);
        }
        __syncthreads();
    }

    // ---- prefetch first 8 support_y rows (independent of wv) ----
    const float* ybase = y + ((size_t)b * SS + srow0) * CC + tid * 4;
    float4 yReg[8];
    if (tid < 250) {
        #pragma unroll
        for (int i = 0; i < 8; i++)
            yReg[i] = *(const float4*)(ybase + (size_t)i * CC);
    }

    // ---- Epilogue: per-row ||.||^2 -> wv[row] = exp(-sqrt(.)) ----
    // C/D layout: col = wcol + n*16 + lr ; row = wrow + m*16 + lg*4 + j
    float rp[4][4];
    #pragma unroll
    for (int m = 0; m < 4; m++)
        #pragma unroll
        for (int j = 0; j < 4; j++) {
            float s = 0.f;
            #pragma unroll
            for (int n = 0; n < 4; n++) { float v = acc[m][n][j]; s += v * v; }
            rp[m][j] = s;
        }
    #pragma unroll
    for (int mask = 1; mask < 16; mask <<= 1)
        #pragma unroll
        for (int m = 0; m < 4; m++)
            #pragma unroll
            for (int j = 0; j < 4; j++)
                rp[m][j] += __shfl_xor(rp[m][j], mask);

    if (lr == 0) {
        #pragma unroll
        for (int m = 0; m < 4; m++)
            #pragma unroll
            for (int j = 0; j < 4; j++)
                scp[w & 1][wrow + m * 16 + lg * 4 + j] = rp[m][j];
    }
    __syncthreads();
    if (tid < 128)
        wv[tid] = expf(-sqrtf(scp[0][tid] + scp[1][tid]));
    __syncthreads();

    // partial denominator: wave 0 reduces wv[0..127]
    if (w == 0) {
        float d = wv[lane] + wv[lane + 64];
        #pragma unroll
        for (int mask = 1; mask < 64; mask <<= 1)
            d += __shfl_xor(d, mask);
        if (lane == 0) pden[b * 64 + chunk] = d;
    }

    // ---- Phase 2: weighted partial sum over support_y (128 rows x 1000 classes) ----
    if (tid < 250) {
        float a0 = 0.f, a1 = 0.f, a2 = 0.f, a3 = 0.f;
        for (int r0 = 0; r0 < 128; r0 += 8) {
            #pragma unroll
            for (int i = 0; i < 8; i++) {
                float4 v = yReg[i];
                float wgt = wv[r0 + i];
                a0 += wgt * v.x; a1 += wgt * v.y; a2 += wgt * v.z; a3 += wgt * v.w;
                if (r0 + 8 + i < 128)
                    yReg[i] = *(const float4*)(ybase + (size_t)(r0 + 8 + i) * CC);
            }
        }
        float4 res = {a0, a1, a2, a3};
        *(float4*)(pout + ((size_t)(b * 64 + chunk)) * CC + tid * 4) = res;
    }
}

// ---------------- K4: final reduction over 64 chunks ----------------
__global__ void k4_final(const float* __restrict__ pout, const float* __restrict__ pden,
                         float* __restrict__ out) {
    int idx = blockIdx.x * 256 + threadIdx.x;
    if (idx >= BB * CC) return;
    int b = idx / CC, c = idx % CC;
    float den = 0.f;
    #pragma unroll 8
    for (int k = 0; k < 64; k++) den += pden[b * 64 + k];
    float num = 0.f;
    #pragma unroll 8
    for (int k = 0; k < 64; k++) num += pout[((size_t)(b * 64 + k)) * CC + c];
    out[idx] = num / den;
}

extern "C" void kernel_launch(void* const* d_in, const int* in_sizes, int n_in,
                              void* d_out, int out_size, void* d_ws, size_t ws_size,
                              hipStream_t stream) {
    const float* x  = (const float*)d_in[0];
    const float* sx = (const float*)d_in[1];
    const float* sy = (const float*)d_in[2];
    const float* W  = (const float*)d_in[3];

    char* ws = (char*)d_ws;
    __bf16* Wt   = (__bf16*)(ws);                        // 131072 B
    float*  pout = (float*)(ws + 131072);                // 2048000 B
    float*  pden = (float*)(ws + 131072 + 2048000);      // 2048 B

    k0_wt<<<256, 256, 0, stream>>>(W, Wt);
    k_fused<<<512, 256, 0, stream>>>(x, sx, Wt, sy, pout, pden);
    k4_final<<<32, 256, 0, stream>>>(pout, pden, (float*)d_out);
}